// Round 12
// baseline (1167.681 us; speedup 1.0000x reference)
//
#include <hip/hip_runtime.h>
#include <hip/hip_bf16.h>

#define N_NODES 50000
#define E_EDGES 800000
#define IN_F 128
#define H_HEADS 8
#define C_CH 32
#define HC 256                   // H*C
#define G_GRAPHS 64
#define NEG_SLOPE 0.2f
#define NCHUNK 49                // ceil(N/1024)

__device__ __forceinline__ unsigned short f2bf(float f) {   // RNE float->bf16
    unsigned u = __float_as_uint(f);
    u += 0x7fffu + ((u >> 16) & 1u);
    return (unsigned short)(u >> 16);
}

// h_bf = bf16(x@W) [N,256]; a_src/a_dst = per-(node,head) fp32 logits.
__global__ __launch_bounds__(256) void k_gemm(const float* __restrict__ x,
        const float* __restrict__ W, const float* __restrict__ att_src,
        const float* __restrict__ att_dst, unsigned short* __restrict__ hb,
        float* __restrict__ a_src, float* __restrict__ a_dst) {
    __shared__ float xs[8 * IN_F];
    const int n0 = blockIdx.x * 8;
    const int tid = threadIdx.x;
    ((float4*)xs)[tid] = ((const float4*)(x + (size_t)n0 * IN_F))[tid];
    __syncthreads();

    const int j = tid;            // output column 0..255
    float acc[8];
    #pragma unroll
    for (int r = 0; r < 8; ++r) acc[r] = 0.f;

    const float4* xs4 = (const float4*)xs;
    for (int k4 = 0; k4 < IN_F / 4; ++k4) {
        const float w0 = W[(k4 * 4 + 0) * HC + j];
        const float w1 = W[(k4 * 4 + 1) * HC + j];
        const float w2 = W[(k4 * 4 + 2) * HC + j];
        const float w3 = W[(k4 * 4 + 3) * HC + j];
        #pragma unroll
        for (int r = 0; r < 8; ++r) {
            float4 xv = xs4[r * (IN_F / 4) + k4];
            acc[r] += xv.x * w0 + xv.y * w1 + xv.z * w2 + xv.w * w3;
        }
    }

    const float asv = att_src[j], adv = att_dst[j];
    const int hh = j >> 5;
    #pragma unroll
    for (int r = 0; r < 8; ++r) {
        hb[(size_t)(n0 + r) * HC + j] = f2bf(acc[r]);
        float s = acc[r] * asv, d = acc[r] * adv;
        #pragma unroll
        for (int off = 16; off; off >>= 1) {
            s += __shfl_xor(s, off, 64);
            d += __shfl_xor(d, off, 64);
        }
        if ((tid & 31) == 0) {
            a_src[(n0 + r) * H_HEADS + hh] = s;
            a_dst[(n0 + r) * H_HEADS + hh] = d;
        }
    }
}

// in-degree histogram (real edges only; self-loops handled by k_selfloop)
__global__ __launch_bounds__(256) void k_hist(const int* __restrict__ ei,
        int* __restrict__ deg) {
    int i = blockIdx.x * 256 + threadIdx.x;
    if (i < E_EDGES) atomicAdd(deg + ei[E_EDGES + i], 1);
}

// per-1024-node chunk sums of deg — contention-free reduction, 49 blocks
__global__ __launch_bounds__(256) void k_chunksum(const int* __restrict__ deg,
        int* __restrict__ chunk) {
    __shared__ int ws4[4];
    const int tid = threadIdx.x, lane = tid & 63, wid = tid >> 6;
    const int base = blockIdx.x * 1024 + tid * 4;
    int s = 0;
    #pragma unroll
    for (int u = 0; u < 4; ++u) {
        int i = base + u;
        if (i < N_NODES) s += deg[i];
    }
    #pragma unroll
    for (int o = 32; o; o >>= 1) s += __shfl_xor(s, o, 64);
    if (lane == 0) ws4[wid] = s;
    __syncthreads();
    if (tid == 0) chunk[blockIdx.x] = ws4[0] + ws4[1] + ws4[2] + ws4[3];
}

// exclusive scan of the 49 chunk sums (one wave)
__global__ __launch_bounds__(64) void k_chunkscan(const int* __restrict__ chunk,
        int* __restrict__ chunkoff) {
    int t = threadIdx.x;
    int v = (t < NCHUNK) ? chunk[t] : 0;
    int s = v;
    #pragma unroll
    for (int d = 1; d < 64; d <<= 1) {
        int u = __shfl_up(s, d, 64);
        if (t >= d) s += u;
    }
    if (t < NCHUNK) chunkoff[t] = s - v;
}

// per-chunk local scan (+ chunk base) -> cursor
__global__ __launch_bounds__(1024) void k_localscan(const int* __restrict__ deg,
        const int* __restrict__ chunkoff, int* __restrict__ cursor) {
    __shared__ int wsum[16];
    const int tid = threadIdx.x, lane = tid & 63, wid = tid >> 6;
    const int i = blockIdx.x * 1024 + tid;
    int v = (i < N_NODES) ? deg[i] : 0;
    int s = v;
    #pragma unroll
    for (int d = 1; d < 64; d <<= 1) {
        int t = __shfl_up(s, d, 64);
        if (lane >= d) s += t;
    }
    if (lane == 63) wsum[wid] = s;
    __syncthreads();
    if (wid == 0 && lane < 16) {
        int t = wsum[lane];
        #pragma unroll
        for (int d = 1; d < 16; d <<= 1) {
            int u = __shfl_up(t, d, 64);
            if (lane >= d) t += u;
        }
        wsum[lane] = t;
    }
    __syncthreads();
    int wpre = wid ? wsum[wid - 1] : 0;
    if (i < N_NODES) cursor[i] = chunkoff[blockIdx.x] + wpre + s - v;
}

// scatter (src, dst) into dst-sorted edge arrays
__global__ __launch_bounds__(256) void k_scatter(const int* __restrict__ ei,
        int* __restrict__ cursor, int* __restrict__ csr_src,
        int* __restrict__ csr_dst) {
    int i = blockIdx.x * 256 + threadIdx.x;
    if (i >= E_EDGES) return;
    int dst = ei[E_EDGES + i];
    int p = atomicAdd(cursor + dst, 1);
    csr_src[p] = ei[i];
    csr_dst[p] = dst;
}

__device__ __forceinline__ void bf4_unpack(uint2 q, float& x0, float& x1,
                                           float& x2, float& x3) {
    x0 = __uint_as_float(q.x << 16);
    x1 = __uint_as_float(q.x & 0xffff0000u);
    x2 = __uint_as_float(q.y << 16);
    x3 = __uint_as_float(q.y & 0xffff0000u);
}

// Self-loop contribution INITIALIZES outacc/den with plain coalesced stores
// (replaces a 53MB memset; must run before k_edge). One wave per node.
__global__ __launch_bounds__(256) void k_selfloop(const unsigned short* __restrict__ hb,
        const float* __restrict__ a_src, const float* __restrict__ a_dst,
        float* __restrict__ outacc, float* __restrict__ den) {
    const int wave = threadIdx.x >> 6, lane = threadIdx.x & 63;
    const int n = blockIdx.x * 4 + wave;
    if (n >= N_NODES) return;
    const int hh = lane >> 3;
    float e = a_src[n * H_HEADS + hh] + a_dst[n * H_HEADS + hh];
    e = e > 0.f ? e : NEG_SLOPE * e;
    float w = __expf(e);
    uint2 q = ((const uint2*)(hb + (size_t)n * HC))[lane];
    float x0, x1, x2, x3; bf4_unpack(q, x0, x1, x2, x3);
    float* oa = outacc + (size_t)n * HC + lane * 4;
    oa[0] = w * x0; oa[1] = w * x1; oa[2] = w * x2; oa[3] = w * x3;
    if ((lane & 7) == 0) den[n * H_HEADS + hh] = w;
}

// Edge-balanced: each wave = exactly 8 consecutive edges of the dst-sorted
// stream. All 8 row-gathers issued up front; in-register segmented
// accumulation; atomic flush at dst boundaries (~1.5 flushes/wave avg).
// 100K identical waves -> full occupancy, zero imbalance.
__global__ __launch_bounds__(256) void k_edge(const unsigned short* __restrict__ hb,
        const float* __restrict__ a_src, const float* __restrict__ a_dst,
        const int* __restrict__ csr_src, const int* __restrict__ csr_dst,
        float* __restrict__ outacc, float* __restrict__ den) {
    const int wid = blockIdx.x * 4 + (threadIdx.x >> 6);
    const int lane = threadIdx.x & 63;
    const int kb = wid * 8;
    if (kb >= E_EDGES) return;
    const int hh = lane >> 3;              // lane covers channels 4*lane..+3

    int s[8], d[8];
    #pragma unroll
    for (int u = 0; u < 8; ++u) { s[u] = csr_src[kb + u]; d[u] = csr_dst[kb + u]; }
    uint2 q[8];
    #pragma unroll
    for (int u = 0; u < 8; ++u)
        q[u] = ((const uint2*)(hb + (size_t)s[u] * HC))[lane];
    float w[8];
    #pragma unroll
    for (int u = 0; u < 8; ++u) {
        float e = a_src[s[u] * H_HEADS + hh] + a_dst[d[u] * H_HEADS + hh];
        e = e > 0.f ? e : NEG_SLOPE * e;
        w[u] = __expf(e);
    }

    float a0 = 0.f, a1 = 0.f, a2 = 0.f, a3 = 0.f, dn = 0.f;
    #pragma unroll
    for (int u = 0; u < 8; ++u) {
        float x0, x1, x2, x3; bf4_unpack(q[u], x0, x1, x2, x3);
        a0 += w[u] * x0; a1 += w[u] * x1;
        a2 += w[u] * x2; a3 += w[u] * x3;
        dn += w[u];
        bool fl = (u == 7) ? true : (d[u + 1] != d[u]);   // wave-uniform branch
        if (fl) {
            float* oa = outacc + (size_t)d[u] * HC + lane * 4;
            atomicAdd(oa + 0, a0); atomicAdd(oa + 1, a1);
            atomicAdd(oa + 2, a2); atomicAdd(oa + 3, a3);
            if ((lane & 7) == 0) atomicAdd(den + d[u] * H_HEADS + hh, dn);
            a0 = a1 = a2 = a3 = dn = 0.f;
        }
    }
}

// normalize per head, head-mean, +bias, relu, pool atomics
__global__ __launch_bounds__(256) void k_finalize(const float* __restrict__ outacc,
        const float* __restrict__ den, const float* __restrict__ bias,
        const int* __restrict__ batch, float* __restrict__ pool,
        float* __restrict__ cnt) {
    int idx = blockIdx.x * 256 + threadIdx.x;   // over N*C
    if (idx >= N_NODES * C_CH) return;
    int n = idx >> 5, c = idx & 31;
    float s = 0.f;
    #pragma unroll
    for (int hh = 0; hh < H_HEADS; ++hh)
        s += outacc[(size_t)n * HC + hh * C_CH + c]
             / (den[n * H_HEADS + hh] + 1e-16f);
    s = s * 0.125f + bias[c];
    s = s > 0.f ? s : 0.f;                      // relu
    int g = batch[n];
    atomicAdd(pool + g * C_CH + c, s);
    if (c == 0) atomicAdd(cnt + g, 1.f);
}

// Final: pooled mean + [G,2] linear; writes x_t then pooled into d_out.
__global__ __launch_bounds__(256) void k_final(const float* __restrict__ pool,
        const float* __restrict__ cnt, const float* __restrict__ lin_w,
        const float* __restrict__ lin_b, float* __restrict__ out) {
    __shared__ float pd[G_GRAPHS * C_CH];
    int t = threadIdx.x;
    for (int i = t; i < G_GRAPHS * C_CH; i += 256) {
        int g = i >> 5;
        float p = pool[i] / fmaxf(cnt[g], 1.f);
        pd[i] = p;
        out[G_GRAPHS * 2 + i] = p;              // pooled output (tuple elem 2)
    }
    __syncthreads();
    if (t < G_GRAPHS * 2) {
        int g = t >> 1, o = t & 1;
        float s = lin_b[o];
        #pragma unroll
        for (int c = 0; c < C_CH; ++c) s += pd[g * C_CH + c] * lin_w[c * 2 + o];
        out[t] = s;                             // x_t output (tuple elem 1)
    }
}

extern "C" void kernel_launch(void* const* d_in, const int* in_sizes, int n_in,
                              void* d_out, int out_size, void* d_ws, size_t ws_size,
                              hipStream_t stream) {
    const float* x       = (const float*)d_in[0];
    const int*   ei      = (const int*)d_in[1];
    const int*   batch   = (const int*)d_in[2];
    const float* W       = (const float*)d_in[3];
    const float* att_src = (const float*)d_in[4];
    const float* att_dst = (const float*)d_in[5];
    const float* bias    = (const float*)d_in[6];
    const float* lin_w   = (const float*)d_in[7];
    const float* lin_b   = (const float*)d_in[8];

    char* ws = (char*)d_ws;
    unsigned short* hb   = (unsigned short*)(ws);   // 25,600,000
    float* a_src   = (float*)(ws + 25600000);       //  1,600,000
    float* a_dst   = (float*)(ws + 27200000);       //  1,600,000
    int*   deg     = (int*)  (ws + 28800000);       //    200,000
    int*   chunk   = (int*)  (ws + 29000000);       //        256
    int*   cursor  = (int*)  (ws + 29000256);       //    200,000
    int*   csr_src = (int*)  (ws + 29200256);       //  3,200,000
    int*   csr_dst = (int*)  (ws + 32400256);       //  3,200,000
    float* pool    = (float*)(ws + 35600256);       //      8,192
    float* cnt     = (float*)(ws + 35608448);       //        256
    int*   chunkoff= (int*)  (ws + 35608704);       //        256
    float* outacc  = (float*)(ws + 35608960);       // 51,200,000
    float* den     = (float*)(ws + 86808960);       //  1,600,000
    // total ~88.4 MB

    hipMemsetAsync(deg, 0, 200000, stream);
    hipMemsetAsync(pool, 0, 8192 + 256, stream);    // pool + cnt contiguous

    k_gemm<<<N_NODES / 8, 256, 0, stream>>>(x, W, att_src, att_dst, hb, a_src, a_dst);
    k_hist<<<(E_EDGES + 255) / 256, 256, 0, stream>>>(ei, deg);
    k_chunksum<<<NCHUNK, 256, 0, stream>>>(deg, chunk);
    k_chunkscan<<<1, 64, 0, stream>>>(chunk, chunkoff);
    k_localscan<<<NCHUNK, 1024, 0, stream>>>(deg, chunkoff, cursor);
    k_scatter<<<(E_EDGES + 255) / 256, 256, 0, stream>>>(ei, cursor, csr_src, csr_dst);
    k_selfloop<<<(N_NODES + 3) / 4, 256, 0, stream>>>(hb, a_src, a_dst, outacc, den);
    k_edge<<<(E_EDGES / 8 + 3) / 4, 256, 0, stream>>>(
        hb, a_src, a_dst, csr_src, csr_dst, outacc, den);
    k_finalize<<<(N_NODES * C_CH + 255) / 256, 256, 0, stream>>>(
        outacc, den, bias, batch, pool, cnt);
    k_final<<<1, 256, 0, stream>>>(pool, cnt, lin_w, lin_b, (float*)d_out);
}

// Round 15
// 707.424 us; speedup vs baseline: 1.6506x; 1.6506x over previous
//
#include <hip/hip_runtime.h>
#include <hip/hip_bf16.h>

#define N_NODES 50000
#define E_EDGES 800000
#define IN_F 128
#define H_HEADS 8
#define C_CH 32
#define HC 256                   // H*C
#define G_GRAPHS 64
#define NEG_SLOPE 0.2f
#define NCHUNK 49                // ceil(N/1024)

__device__ __forceinline__ unsigned short f2bf(float f) {   // RNE float->bf16
    unsigned u = __float_as_uint(f);
    u += 0x7fffu + ((u >> 16) & 1u);
    return (unsigned short)(u >> 16);
}

// h_bf = bf16(x@W) [N,256]; a_src/a_dst = per-(node,head) fp32 logits.
// 8 nodes per block; 256 threads = one output column each.
__global__ __launch_bounds__(256) void k_gemm(const float* __restrict__ x,
        const float* __restrict__ W, const float* __restrict__ att_src,
        const float* __restrict__ att_dst, unsigned short* __restrict__ hb,
        float* __restrict__ a_src, float* __restrict__ a_dst) {
    __shared__ float xs[8 * IN_F];
    const int n0 = blockIdx.x * 8;
    const int tid = threadIdx.x;
    ((float4*)xs)[tid] = ((const float4*)(x + (size_t)n0 * IN_F))[tid];
    __syncthreads();

    const int j = tid;            // output column 0..255
    float acc[8];
    #pragma unroll
    for (int r = 0; r < 8; ++r) acc[r] = 0.f;

    const float4* xs4 = (const float4*)xs;
    for (int k4 = 0; k4 < IN_F / 4; ++k4) {
        const float w0 = W[(k4 * 4 + 0) * HC + j];
        const float w1 = W[(k4 * 4 + 1) * HC + j];
        const float w2 = W[(k4 * 4 + 2) * HC + j];
        const float w3 = W[(k4 * 4 + 3) * HC + j];
        #pragma unroll
        for (int r = 0; r < 8; ++r) {
            float4 xv = xs4[r * (IN_F / 4) + k4];
            acc[r] += xv.x * w0 + xv.y * w1 + xv.z * w2 + xv.w * w3;
        }
    }

    const float asv = att_src[j], adv = att_dst[j];
    const int hh = j >> 5;
    #pragma unroll
    for (int r = 0; r < 8; ++r) {
        hb[(size_t)(n0 + r) * HC + j] = f2bf(acc[r]);
        float s = acc[r] * asv, d = acc[r] * adv;
        #pragma unroll
        for (int off = 16; off; off >>= 1) {   // reduce within each 32-lane head group
            s += __shfl_xor(s, off, 64);
            d += __shfl_xor(d, off, 64);
        }
        if ((tid & 31) == 0) {
            a_src[(n0 + r) * H_HEADS + hh] = s;
            a_dst[(n0 + r) * H_HEADS + hh] = d;
        }
    }
}

// in-degree histogram (real edges only; self-loops handled in k_node)
__global__ __launch_bounds__(256) void k_hist(const int* __restrict__ ei,
        int* __restrict__ deg) {
    int i = blockIdx.x * 256 + threadIdx.x;
    if (i < E_EDGES) atomicAdd(deg + ei[E_EDGES + i], 1);
}

// per-1024-node chunk sums of deg — contention-free reduction, 49 blocks
__global__ __launch_bounds__(256) void k_chunksum(const int* __restrict__ deg,
        int* __restrict__ chunk) {
    __shared__ int ws4[4];
    const int tid = threadIdx.x, lane = tid & 63, wid = tid >> 6;
    const int base = blockIdx.x * 1024 + tid * 4;
    int s = 0;
    #pragma unroll
    for (int u = 0; u < 4; ++u) {
        int i = base + u;
        if (i < N_NODES) s += deg[i];
    }
    #pragma unroll
    for (int o = 32; o; o >>= 1) s += __shfl_xor(s, o, 64);
    if (lane == 0) ws4[wid] = s;
    __syncthreads();
    if (tid == 0) chunk[blockIdx.x] = ws4[0] + ws4[1] + ws4[2] + ws4[3];
}

// exclusive scan of the 49 chunk sums (one wave)
__global__ __launch_bounds__(64) void k_chunkscan(const int* __restrict__ chunk,
        int* __restrict__ chunkoff) {
    int t = threadIdx.x;
    int v = (t < NCHUNK) ? chunk[t] : 0;
    int s = v;
    #pragma unroll
    for (int d = 1; d < 64; d <<= 1) {
        int u = __shfl_up(s, d, 64);
        if (t >= d) s += u;
    }
    if (t < NCHUNK) chunkoff[t] = s - v;
}

// per-chunk local scan (+ chunk base) -> off, cursor
__global__ __launch_bounds__(1024) void k_localscan(const int* __restrict__ deg,
        const int* __restrict__ chunkoff, int* __restrict__ off,
        int* __restrict__ cursor) {
    __shared__ int wsum[16];
    const int tid = threadIdx.x, lane = tid & 63, wid = tid >> 6;
    const int i = blockIdx.x * 1024 + tid;
    int v = (i < N_NODES) ? deg[i] : 0;
    int s = v;
    #pragma unroll
    for (int d = 1; d < 64; d <<= 1) {
        int t = __shfl_up(s, d, 64);
        if (lane >= d) s += t;
    }
    if (lane == 63) wsum[wid] = s;
    __syncthreads();
    if (wid == 0 && lane < 16) {
        int t = wsum[lane];
        #pragma unroll
        for (int d = 1; d < 16; d <<= 1) {
            int u = __shfl_up(t, d, 64);
            if (lane >= d) t += u;
        }
        wsum[lane] = t;
    }
    __syncthreads();
    int wpre = wid ? wsum[wid - 1] : 0;
    if (i < N_NODES) {
        int excl = chunkoff[blockIdx.x] + wpre + s - v;
        off[i] = excl;
        cursor[i] = excl;
    }
    if (blockIdx.x == NCHUNK - 1 && tid == 0) off[N_NODES] = E_EDGES;
}

// scatter src indices into CSR-by-dst
__global__ __launch_bounds__(256) void k_scatter(const int* __restrict__ ei,
        int* __restrict__ cursor, int* __restrict__ csr_src) {
    int i = blockIdx.x * 256 + threadIdx.x;
    if (i >= E_EDGES) return;
    int dst = ei[E_EDGES + i];
    int p = atomicAdd(cursor + dst, 1);
    csr_src[p] = ei[i];
}

__device__ __forceinline__ void bf4_unpack(uint2 q, float& x0, float& x1,
                                           float& x2, float& x3) {
    x0 = __uint_as_float(q.x << 16);
    x1 = __uint_as_float(q.x & 0xffff0000u);
    x2 = __uint_as_float(q.y << 16);
    x3 = __uint_as_float(q.y & 0xffff0000u);
}

// One 64-lane wave per destination node. Lane l: head hh=l>>3, channels
// 4*(l&7)..+3. bf16 h rows = 512B, lane loads uint2 (4 channels).
// SINGLE pass, 4-wide batched (round-8 pass-2 structure, low VGPR).
// No max-subtraction: softmax ratio is invariant and logits are bounded
// (|e| <~ 5 from N(0,~0.6) h and N(0,~0.3) att vectors; exp < 150 << fp32
// overflow at e=88). Validated: absmax 1.2e-4 (round 9).
__global__ __launch_bounds__(256) void k_node(const unsigned short* __restrict__ hb,
        const float* __restrict__ a_src, const float* __restrict__ a_dst,
        const int* __restrict__ off, const int* __restrict__ csr_src,
        const int* __restrict__ batch, const float* __restrict__ bias,
        float* __restrict__ pool, float* __restrict__ cnt) {
    const int wave = threadIdx.x >> 6, lane = threadIdx.x & 63;
    const int n = blockIdx.x * 4 + wave;
    if (n >= N_NODES) return;
    const int hh = lane >> 3;
    const int beg = off[n], end = off[n + 1];
    const float adst = a_dst[n * H_HEADS + hh];

    float denom = 0.f;
    float ax = 0.f, ay = 0.f, az = 0.f, aw = 0.f;
    {   // self-loop
        float e = a_src[n * H_HEADS + hh] + adst;
        e = e > 0.f ? e : NEG_SLOPE * e;
        float w = __expf(e);
        denom += w;
        uint2 q = ((const uint2*)(hb + (size_t)n * HC))[lane];
        float x0, x1, x2, x3; bf4_unpack(q, x0, x1, x2, x3);
        ax += w * x0; ay += w * x1; az += w * x2; aw += w * x3;
    }

    int k = beg;
    for (; k + 3 < end; k += 4) {
        int s[4];
        s[0] = csr_src[k]; s[1] = csr_src[k + 1];
        s[2] = csr_src[k + 2]; s[3] = csr_src[k + 3];
        uint2 q[4];
        #pragma unroll
        for (int u = 0; u < 4; ++u)
            q[u] = ((const uint2*)(hb + (size_t)s[u] * HC))[lane];
        #pragma unroll
        for (int u = 0; u < 4; ++u) {
            float e = a_src[s[u] * H_HEADS + hh] + adst;
            e = e > 0.f ? e : NEG_SLOPE * e;
            float w = __expf(e);
            denom += w;
            float x0, x1, x2, x3; bf4_unpack(q[u], x0, x1, x2, x3);
            ax += w * x0; ay += w * x1; az += w * x2; aw += w * x3;
        }
    }
    for (; k < end; ++k) {
        int src = csr_src[k];
        float e = a_src[src * H_HEADS + hh] + adst;
        e = e > 0.f ? e : NEG_SLOPE * e;
        float w = __expf(e);
        denom += w;
        uint2 q = ((const uint2*)(hb + (size_t)src * HC))[lane];
        float x0, x1, x2, x3; bf4_unpack(q, x0, x1, x2, x3);
        ax += w * x0; ay += w * x1; az += w * x2; aw += w * x3;
    }

    const float inv = 1.f / (denom + 1e-16f);
    float rx = ax * inv, ry = ay * inv, rz = az * inv, rw = aw * inv;
    // head mean: reduce across the 8 lanes sharing (lane&7)
    #pragma unroll
    for (int o = 8; o < 64; o <<= 1) {
        rx += __shfl_xor(rx, o, 64);
        ry += __shfl_xor(ry, o, 64);
        rz += __shfl_xor(rz, o, 64);
        rw += __shfl_xor(rw, o, 64);
    }
    if (lane < 8) {
        const int c0 = lane * 4;
        const int g = batch[n];
        float o0 = fmaxf(rx * 0.125f + bias[c0 + 0], 0.f);
        float o1 = fmaxf(ry * 0.125f + bias[c0 + 1], 0.f);
        float o2 = fmaxf(rz * 0.125f + bias[c0 + 2], 0.f);
        float o3 = fmaxf(rw * 0.125f + bias[c0 + 3], 0.f);
        float* pg = pool + g * C_CH + c0;
        atomicAdd(pg + 0, o0); atomicAdd(pg + 1, o1);
        atomicAdd(pg + 2, o2); atomicAdd(pg + 3, o3);
        if (lane == 0) atomicAdd(cnt + g, 1.f);
    }
}

// Final: pooled mean + [G,2] linear; writes x_t then pooled into d_out.
__global__ __launch_bounds__(256) void k_final(const float* __restrict__ pool,
        const float* __restrict__ cnt, const float* __restrict__ lin_w,
        const float* __restrict__ lin_b, float* __restrict__ out) {
    __shared__ float pd[G_GRAPHS * C_CH];
    int t = threadIdx.x;
    for (int i = t; i < G_GRAPHS * C_CH; i += 256) {
        int g = i >> 5;
        float p = pool[i] / fmaxf(cnt[g], 1.f);
        pd[i] = p;
        out[G_GRAPHS * 2 + i] = p;              // pooled output (tuple elem 2)
    }
    __syncthreads();
    if (t < G_GRAPHS * 2) {
        int g = t >> 1, o = t & 1;
        float s = lin_b[o];
        #pragma unroll
        for (int c = 0; c < C_CH; ++c) s += pd[g * C_CH + c] * lin_w[c * 2 + o];
        out[t] = s;                             // x_t output (tuple elem 1)
    }
}

extern "C" void kernel_launch(void* const* d_in, const int* in_sizes, int n_in,
                              void* d_out, int out_size, void* d_ws, size_t ws_size,
                              hipStream_t stream) {
    const float* x       = (const float*)d_in[0];
    const int*   ei      = (const int*)d_in[1];
    const int*   batch   = (const int*)d_in[2];
    const float* W       = (const float*)d_in[3];
    const float* att_src = (const float*)d_in[4];
    const float* att_dst = (const float*)d_in[5];
    const float* bias    = (const float*)d_in[6];
    const float* lin_w   = (const float*)d_in[7];
    const float* lin_b   = (const float*)d_in[8];

    char* ws = (char*)d_ws;
    unsigned short* hb   = (unsigned short*)(ws);   // 25,600,000
    float* a_src   = (float*)(ws + 25600000);       //  1,600,000
    float* a_dst   = (float*)(ws + 27200000);       //  1,600,000
    int*   deg     = (int*)  (ws + 28800000);       //    200,000
    int*   chunk   = (int*)  (ws + 29000000);       //        256
    int*   off     = (int*)  (ws + 29000256);       //    200,064
    int*   cursor  = (int*)  (ws + 29200512);       //    200,000
    int*   csr_src = (int*)  (ws + 29400512);       //  3,200,000
    float* pool    = (float*)(ws + 32600512);       //      8,192
    float* cnt     = (float*)(ws + 32608704);       //        256
    int*   chunkoff= (int*)  (ws + 32608960);       //        256
    // total ~32.6 MB

    hipMemsetAsync(deg, 0, 200000, stream);
    hipMemsetAsync(pool, 0, 8192 + 256, stream);    // pool + cnt contiguous

    k_gemm<<<N_NODES / 8, 256, 0, stream>>>(x, W, att_src, att_dst, hb, a_src, a_dst);
    k_hist<<<(E_EDGES + 255) / 256, 256, 0, stream>>>(ei, deg);
    k_chunksum<<<NCHUNK, 256, 0, stream>>>(deg, chunk);
    k_chunkscan<<<1, 64, 0, stream>>>(chunk, chunkoff);
    k_localscan<<<NCHUNK, 1024, 0, stream>>>(deg, chunkoff, off, cursor);
    k_scatter<<<(E_EDGES + 255) / 256, 256, 0, stream>>>(ei, cursor, csr_src);
    k_node<<<(N_NODES + 3) / 4, 256, 0, stream>>>(
        hb, a_src, a_dst, off, csr_src, batch, bias, pool, cnt);
    k_final<<<1, 256, 0, stream>>>(pool, cnt, lin_w, lin_b, (float*)d_out);
}